// Round 4
// baseline (681.800 us; speedup 1.0000x reference)
//
#include <hip/hip_runtime.h>
#include <math.h>

#define ZR 128
#define NR 512
#define ZB1 4096

typedef unsigned int u32x4 __attribute__((ext_vector_type(4)));
typedef unsigned short u16x8 __attribute__((ext_vector_type(8)));
typedef unsigned long long u64x2v __attribute__((ext_vector_type(2)));

// tiled albedo layout: bf16, tile = 4(x) x 8(y) = 32 elems = 64 B (one cache line)
// element index: ((z*128 + (x>>2)) << 11) | ((y>>3) << 5) | ((x&3) << 3) | (y&7)
// each (z,x) row of 8 y-values is 16 B contiguous & aligned -> one dwordx4 load
// total: 128 * 128 * 64 * 32 = 33,554,432 elems = 64 MiB

__device__ __forceinline__ float bf16_to_f32(unsigned short u) {
    return __uint_as_float(((unsigned int)u) << 16);
}

__device__ __forceinline__ unsigned short f32_to_bf16_rne(float v) {
    unsigned int u = __float_as_uint(v);
    return (unsigned short)((u + 0x7FFFu + ((u >> 16) & 1u)) >> 16);
}

__device__ __forceinline__ float extract_bf16(u64x2v v, int yo) {
    unsigned long long w = (yo & 4) ? v.y : v.x;
    unsigned int sh = ((unsigned)yo & 3u) << 4;
    return bf16_to_f32((unsigned short)(w >> sh));
}

// unroll-2 so 2 loads stay in flight per thread (keeps the stream BW-bound)
__device__ __forceinline__ void zcheck_range(
    const u32x4* __restrict__ normal4, long long lo, long long hi,
    long long rank, long long nthreads, unsigned int* __restrict__ flag)
{
    unsigned int acc = 0;
    long long i = lo + rank * 256 + threadIdx.x;
    for (; i + nthreads < hi; i += 2 * nthreads) {
        u32x4 v0 = __builtin_nontemporal_load(&normal4[i]);
        u32x4 v1 = __builtin_nontemporal_load(&normal4[i + nthreads]);
        acc |= v0.x | v0.y | v0.z | v0.w | v1.x | v1.y | v1.z | v1.w;
    }
    if (i < hi) {
        u32x4 v = __builtin_nontemporal_load(&normal4[i]);
        acc |= v.x | v.y | v.z | v.w;
    }
    if (__ballot(acc != 0) && ((threadIdx.x & 63) == 0))
        atomicOr(flag, 1u);
}

// 4 x 16B row-gather + in-register y extraction. Bit-identical tap values and
// FP add order vs the per-tap scalar version (absmax preserved).
__device__ __forceinline__ float interp_rows(
    const unsigned short* __restrict__ tiled,
    float cz, float cx, float cy)
{
    float fz0 = floorf(cz), fx0 = floorf(cx), fy0 = floorf(cy);
    float fz = cz - fz0, fx = cx - fx0, fy = cy - fy0;

    int z0 = min(max((int)fz0, 0), ZR - 1);
    int x0 = min(max((int)fx0, 0), NR - 1);
    int y0 = min(max((int)fy0, 0), NR - 1);
    int z1 = min(z0 + 1, ZR - 1);
    int x1 = min(x0 + 1, NR - 1);
    int y1 = min(y0 + 1, NR - 1);

    float gz = 1.0f - fz, gx = 1.0f - fx, gy = 1.0f - fy;

    float w000 = gz * gx * gy, w001 = gz * gx * fy;
    float w010 = gz * fx * gy, w011 = gz * fx * fy;
    float w100 = fz * gx * gy, w101 = fz * gx * fy;
    float w110 = fz * fx * gy, w111 = fz * fx * fy;

    int xo0 = (x0 & 3) << 3, xo1 = (x1 & 3) << 3;
    int yo0 = y0 & 7,        yo1 = y1 & 7;
    int c0 = (y0 >> 3) << 5, c1 = (y1 >> 3) << 5;
    int r00 = ((z0 << 7) + (x0 >> 2)) << 11;
    int r01 = ((z0 << 7) + (x1 >> 2)) << 11;
    int r10 = ((z1 << 7) + (x0 >> 2)) << 11;
    int r11 = ((z1 << 7) + (x1 >> 2)) << 11;

    const u64x2v* base = (const u64x2v*)tiled;    // 16 B units (8 bf16)

    u64x2v vA = base[(r00 + c0 + xo0) >> 3];      // z0,x0 row
    u64x2v vB = base[(r01 + c0 + xo1) >> 3];      // z0,x1 row
    u64x2v vC = base[(r10 + c0 + xo0) >> 3];      // z1,x0 row
    u64x2v vD = base[(r11 + c0 + xo1) >> 3];      // z1,x1 row

    u64x2v vA2 = vA, vB2 = vB, vC2 = vC, vD2 = vD;
    if (c1 != c0) {                               // y-pair crosses the 8-tile (1/8 of lanes)
        vA2 = base[(r00 + c1 + xo0) >> 3];
        vB2 = base[(r01 + c1 + xo1) >> 3];
        vC2 = base[(r10 + c1 + xo0) >> 3];
        vD2 = base[(r11 + c1 + xo1) >> 3];
    }

    return
        extract_bf16(vA,  yo0) * w000 + extract_bf16(vA2, yo1) * w001 +
        extract_bf16(vB,  yo0) * w010 + extract_bf16(vB2, yo1) * w011 +
        extract_bf16(vC,  yo0) * w100 + extract_bf16(vC2, yo1) * w101 +
        extract_bf16(vD,  yo0) * w110 + extract_bf16(vD2, yo1) * w111;
}

// ---------------- kernel 1: ALL zcheck + albedo repack + out_n constant fill ----------------
// grid = ZB1 (zcheck, all 402 MB) + 16384 (repack) + FB (out_n fill)
__global__ __launch_bounds__(256) void phase1_kernel(
    const float* __restrict__ albedo,
    unsigned short* __restrict__ tiled,
    const u32x4* __restrict__ normal4,
    const unsigned int* __restrict__ normal_tail, int tail_cnt,
    unsigned int* __restrict__ flag,
    float* __restrict__ out_n,
    long long n4, int M, int FB)
{
    unsigned int b = blockIdx.x;

    if (b < (unsigned)ZB1) {
        // zcheck role: long-pole streaming, scheduled first
        if (b == 0 && threadIdx.x < (unsigned)tail_cnt) {
            if (normal_tail[threadIdx.x]) atomicOr(flag, 1u);
        }
        zcheck_range(normal4, 0, n4, (long long)b, (long long)ZB1 * 256, flag);
        return;
    }
    b -= (unsigned)ZB1;

    if (b < 16384u) {
        // repack role: one block per (z, x-tile)
        int z = (int)(b >> 7);
        int xt = (int)(b & 127u);

        __shared__ float s[2048];             // 4 x-rows x 512 y
        const u32x4* src = (const u32x4*)(albedo + ((size_t)z * NR + (size_t)xt * 4) * NR);
        for (int k = threadIdx.x; k < 512; k += 256) {
            u32x4 v = __builtin_nontemporal_load(&src[k]);
            ((u32x4*)s)[k] = v;
        }
        __syncthreads();

        unsigned short* dst = tiled + (size_t)b * 2048;
        int t8 = threadIdx.x * 8;
        u16x8 outv;
#pragma unroll
        for (int j = 0; j < 8; j++) {
            int k = t8 + j;
            int yt = k >> 5;
            int r = k & 31;
            int xr = r >> 3;
            int yy = r & 7;
            outv[j] = f32_to_bf16_rne(s[xr * 512 + (yt << 3) + yy]);
        }
        *(u16x8*)(dst + t8) = outv;           // tiled IS re-read: keep cacheable
        return;
    }
    b -= 16384u;

    // out_n constant-pattern fill role (valid iff flag==0; else overwritten by normal_full)
    // nontemporal: out_n never re-read by us -> don't pollute L2 before the gather phase
    long long total = 3LL * M;
    if ((M & 3) == 0) {
        long long f4 = (long long)b * 256 + threadIdx.x;
        long long nf4 = total >> 2;
        if (f4 < nf4) {
            const unsigned int B = 0xBF800000u;   // -1.0f
            int rmod = (int)(f4 % 3);
            u32x4 v;
            if (rmod == 0)      v = (u32x4){B, 0u, 0u, B};
            else if (rmod == 1) v = (u32x4){0u, 0u, B, 0u};
            else                v = (u32x4){0u, B, 0u, 0u};
            __builtin_nontemporal_store(v, &((u32x4*)out_n)[f4]);
        }
    } else {
        long long stride = (long long)FB * 256;
        for (long long qq = (long long)b * 256 + threadIdx.x; qq < total; qq += stride)
            out_n[qq] = ((qq % 3) == 0) ? -1.0f : 0.0f;
    }
}

// ---------------- kernel 2: PURE interp on tiled albedo, 1 pt/thread ----------------
__global__ __launch_bounds__(256) void interp_kernel(
    const float* __restrict__ coords,
    const unsigned short* __restrict__ tiled,
    float* __restrict__ out_a,
    int M)
{
    int i = blockIdx.x * 256 + threadIdx.x;
    if (i >= M) return;

    float cz = coords[3 * i + 0];
    float cx = coords[3 * i + 1];
    float cy = coords[3 * i + 2];

    float a = interp_rows(tiled, cz, cx, cy);
    a = (a > 0.0f) ? a : expm1f(a);
    __builtin_nontemporal_store(a, &out_a[i]);
}

// ---------------- slow path: recompute out_n when `normal` has content ----------------
__global__ __launch_bounds__(256) void normal_full_kernel(
    const float* __restrict__ coords,
    const float* __restrict__ normal,
    const unsigned int* __restrict__ flag,
    float* __restrict__ out_n,
    int M)
{
    if (*flag == 0) return;

    int stride = gridDim.x * 256;
    for (int i = blockIdx.x * 256 + threadIdx.x; i < M; i += stride) {
        float cz = coords[3 * i + 0];
        float cx = coords[3 * i + 1];
        float cy = coords[3 * i + 2];

        float fz0 = floorf(cz), fx0 = floorf(cx), fy0 = floorf(cy);
        float fz = cz - fz0, fx = cx - fx0, fy = cy - fy0;

        int z0 = min(max((int)fz0, 0), ZR - 1);
        int x0 = min(max((int)fx0, 0), NR - 1);
        int y0 = min(max((int)fy0, 0), NR - 1);
        int z1 = min(z0 + 1, ZR - 1);
        int x1 = min(x0 + 1, NR - 1);
        int y1 = min(y0 + 1, NR - 1);

        float gz = 1.0f - fz, gx = 1.0f - fx, gy = 1.0f - fy;

        float w000 = gz * gx * gy, w001 = gz * gx * fy;
        float w010 = gz * fx * gy, w011 = gz * fx * fy;
        float w100 = fz * gx * gy, w101 = fz * gx * fy;
        float w110 = fz * fx * gy, w111 = fz * fx * fy;

        size_t b00 = ((size_t)z0 * NR + x0) * NR;
        size_t b01 = ((size_t)z0 * NR + x1) * NR;
        size_t b10 = ((size_t)z1 * NR + x0) * NR;
        size_t b11 = ((size_t)z1 * NR + x1) * NR;

        float n0 = 0.0f, n1 = 0.0f, n2 = 0.0f;
#define ACC(base, yy, w)                                           \
        {                                                          \
            const float* qp = normal + ((base) + (size_t)(yy)) * 3;\
            n0 += qp[0] * (w);                                     \
            n1 += qp[1] * (w);                                     \
            n2 += qp[2] * (w);                                     \
        }
        ACC(b00, y0, w000); ACC(b00, y1, w001);
        ACC(b01, y0, w010); ACC(b01, y1, w011);
        ACC(b10, y0, w100); ACC(b10, y1, w101);
        ACC(b11, y0, w110); ACC(b11, y1, w111);
#undef ACC

        n0 = tanhf(n0) - 1.0f;
        n1 = tanhf(n1);
        n2 = tanhf(n2);

        float nrm = sqrtf(n0 * n0 + n1 * n1 + n2 * n2);
        nrm = fmaxf(nrm, 1e-12f);
        float inv = 1.0f / nrm;

        out_n[3 * i + 0] = n0 * inv;
        out_n[3 * i + 1] = n1 * inv;
        out_n[3 * i + 2] = n2 * inv;
    }
}

// ---------------- fallback: fully general direct kernel (ws too small) ----------------
__global__ __launch_bounds__(256) void devox_direct(
    const float* __restrict__ coords,
    const float* __restrict__ albedo,
    const float* __restrict__ normal,
    float* __restrict__ out_a,
    float* __restrict__ out_n,
    int M)
{
    int i = blockIdx.x * 256 + threadIdx.x;
    if (i >= M) return;

    float cz = coords[3 * i + 0];
    float cx = coords[3 * i + 1];
    float cy = coords[3 * i + 2];

    float fz0 = floorf(cz), fx0 = floorf(cx), fy0 = floorf(cy);
    float fz = cz - fz0, fx = cx - fx0, fy = cy - fy0;

    int z0 = min(max((int)fz0, 0), ZR - 1);
    int x0 = min(max((int)fx0, 0), NR - 1);
    int y0 = min(max((int)fy0, 0), NR - 1);
    int z1 = min(z0 + 1, ZR - 1);
    int x1 = min(x0 + 1, NR - 1);
    int y1 = min(y0 + 1, NR - 1);

    float gz = 1.0f - fz, gx = 1.0f - fx, gy = 1.0f - fy;
    float w000 = gz * gx * gy, w001 = gz * gx * fy;
    float w010 = gz * fx * gy, w011 = gz * fx * fy;
    float w100 = fz * gx * gy, w101 = fz * gx * fy;
    float w110 = fz * fx * gy, w111 = fz * fx * fy;

    size_t b00 = ((size_t)z0 * NR + x0) * NR;
    size_t b01 = ((size_t)z0 * NR + x1) * NR;
    size_t b10 = ((size_t)z1 * NR + x0) * NR;
    size_t b11 = ((size_t)z1 * NR + x1) * NR;

    float a =
        albedo[b00 + y0] * w000 + albedo[b00 + y1] * w001 +
        albedo[b01 + y0] * w010 + albedo[b01 + y1] * w011 +
        albedo[b10 + y0] * w100 + albedo[b10 + y1] * w101 +
        albedo[b11 + y0] * w110 + albedo[b11 + y1] * w111;

    float n0 = 0.0f, n1 = 0.0f, n2 = 0.0f;
#define ACC(base, yy, w)                                           \
    {                                                              \
        const float* qp = normal + ((base) + (size_t)(yy)) * 3;    \
        n0 += qp[0] * (w);                                         \
        n1 += qp[1] * (w);                                         \
        n2 += qp[2] * (w);                                         \
    }
    ACC(b00, y0, w000); ACC(b00, y1, w001);
    ACC(b01, y0, w010); ACC(b01, y1, w011);
    ACC(b10, y0, w100); ACC(b10, y1, w101);
    ACC(b11, y0, w110); ACC(b11, y1, w111);
#undef ACC

    a = (a > 0.0f) ? a : expm1f(a);
    n0 = tanhf(n0) - 1.0f;
    n1 = tanhf(n1);
    n2 = tanhf(n2);
    float nrm = sqrtf(n0 * n0 + n1 * n1 + n2 * n2);
    nrm = fmaxf(nrm, 1e-12f);
    float inv = 1.0f / nrm;

    out_a[i] = a;
    out_n[3 * i + 0] = n0 * inv;
    out_n[3 * i + 1] = n1 * inv;
    out_n[3 * i + 2] = n2 * inv;
}

extern "C" void kernel_launch(void* const* d_in, const int* in_sizes, int n_in,
                              void* d_out, int out_size, void* d_ws, size_t ws_size,
                              hipStream_t stream) {
    const float* coords = (const float*)d_in[0];
    const float* albedo = (const float*)d_in[1];
    const float* normal = (const float*)d_in[2];

    int M = in_sizes[0] / 3;
    long long normal_elems = (long long)in_sizes[2];
    long long n4 = normal_elems / 4;
    int tail_cnt = (int)(normal_elems & 3);
    const unsigned int* normal_tail = (const unsigned int*)normal + n4 * 4;

    float* out = (float*)d_out;
    float* out_a = out;
    float* out_n = out + M;

    // ws: [flag u32][pad 256][tiled bf16 albedo: 33,554,432 u16 = 64 MiB]
    size_t tiled_off = 256;
    size_t tiled_bytes = (size_t)128 * 128 * 64 * 32 * 2;
    if (ws_size < tiled_off + tiled_bytes) {
        int nblk = (M + 255) / 256;
        devox_direct<<<nblk, 256, 0, stream>>>(coords, albedo, normal, out_a, out_n, M);
        return;
    }

    unsigned int* flag = (unsigned int*)d_ws;
    unsigned short* tiled = (unsigned short*)((char*)d_ws + tiled_off);

    (void)hipMemsetAsync(flag, 0, sizeof(unsigned int), stream);

    // kernel 1: zcheck ALL of normal (ZB1 blk) + repack (16384 blk) + out_n fill (FB blk)
    long long total_n = 3LL * M;
    int FB = ((M & 3) == 0) ? (int)((total_n / 4 + 255) / 256) : 2048;
    if (FB < 1) FB = 1;
    phase1_kernel<<<ZB1 + 16384 + FB, 256, 0, stream>>>(
        albedo, tiled, (const u32x4*)normal, normal_tail, tail_cnt,
        flag, out_n, n4, M, FB);

    // kernel 2: pure interp, 1 pt/thread
    int iblk = (M + 255) / 256;
    interp_kernel<<<iblk, 256, 0, stream>>>(coords, tiled, out_a, M);

    // slow path (only does work when normal grid has nonzero content)
    normal_full_kernel<<<2048, 256, 0, stream>>>(coords, normal, flag, out_n, M);
}

// Round 5
// 674.466 us; speedup vs baseline: 1.0109x; 1.0109x over previous
//
#include <hip/hip_runtime.h>
#include <math.h>

#define ZR 128
#define NR 512

typedef unsigned int u32x4 __attribute__((ext_vector_type(4)));
typedef unsigned short u16x8 __attribute__((ext_vector_type(8)));
typedef unsigned long long u64x2v __attribute__((ext_vector_type(2)));
typedef float f32x2 __attribute__((ext_vector_type(2)));

// tiled albedo layout: bf16, tile = 4(x) x 8(y) = 32 elems = 64 B (one cache line)
// element index: ((z*128 + (x>>2)) << 11) | ((y>>3) << 5) | ((x&3) << 3) | (y&7)
// each (z,x) row of 8 y-values is 16 B contiguous & aligned -> one dwordx4 load
// total: 128 * 128 * 64 * 32 = 33,554,432 elems = 64 MiB

__device__ __forceinline__ float bf16_to_f32(unsigned short u) {
    return __uint_as_float(((unsigned int)u) << 16);
}

__device__ __forceinline__ unsigned short f32_to_bf16_rne(float v) {
    unsigned int u = __float_as_uint(v);
    return (unsigned short)((u + 0x7FFFu + ((u >> 16) & 1u)) >> 16);
}

__device__ __forceinline__ float extract_bf16(u64x2v v, int yo) {
    unsigned long long w = (yo & 4) ? v.y : v.x;
    unsigned int sh = ((unsigned)yo & 3u) << 4;
    return bf16_to_f32((unsigned short)(w >> sh));
}

// nontemporal stream (bypasses L2 pollution) so the co-scheduled gather keeps
// its tiled working set cache-resident
__device__ __forceinline__ void zcheck_range(
    const u32x4* __restrict__ normal4, long long lo, long long hi,
    long long rank, long long nthreads, unsigned int* __restrict__ flag)
{
    unsigned int acc = 0;
    long long i = lo + rank * 256 + threadIdx.x;
    for (; i + nthreads < hi; i += 2 * nthreads) {
        u32x4 v0 = __builtin_nontemporal_load(&normal4[i]);
        u32x4 v1 = __builtin_nontemporal_load(&normal4[i + nthreads]);
        acc |= v0.x | v0.y | v0.z | v0.w | v1.x | v1.y | v1.z | v1.w;
    }
    if (i < hi) {
        u32x4 v = __builtin_nontemporal_load(&normal4[i]);
        acc |= v.x | v.y | v.z | v.w;
    }
    if (__ballot(acc != 0) && ((threadIdx.x & 63) == 0))
        atomicOr(flag, 1u);
}

// 4 x 16B row-gather + in-register y extraction. Bit-identical tap values and
// FP add order vs the per-tap scalar version (absmax preserved).
__device__ __forceinline__ float interp_rows(
    const unsigned short* __restrict__ tiled,
    float cz, float cx, float cy)
{
    float fz0 = floorf(cz), fx0 = floorf(cx), fy0 = floorf(cy);
    float fz = cz - fz0, fx = cx - fx0, fy = cy - fy0;

    int z0 = min(max((int)fz0, 0), ZR - 1);
    int x0 = min(max((int)fx0, 0), NR - 1);
    int y0 = min(max((int)fy0, 0), NR - 1);
    int z1 = min(z0 + 1, ZR - 1);
    int x1 = min(x0 + 1, NR - 1);
    int y1 = min(y0 + 1, NR - 1);

    float gz = 1.0f - fz, gx = 1.0f - fx, gy = 1.0f - fy;

    float w000 = gz * gx * gy, w001 = gz * gx * fy;
    float w010 = gz * fx * gy, w011 = gz * fx * fy;
    float w100 = fz * gx * gy, w101 = fz * gx * fy;
    float w110 = fz * fx * gy, w111 = fz * fx * fy;

    int xo0 = (x0 & 3) << 3, xo1 = (x1 & 3) << 3;
    int yo0 = y0 & 7,        yo1 = y1 & 7;
    int c0 = (y0 >> 3) << 5, c1 = (y1 >> 3) << 5;
    int r00 = ((z0 << 7) + (x0 >> 2)) << 11;
    int r01 = ((z0 << 7) + (x1 >> 2)) << 11;
    int r10 = ((z1 << 7) + (x0 >> 2)) << 11;
    int r11 = ((z1 << 7) + (x1 >> 2)) << 11;

    const u64x2v* base = (const u64x2v*)tiled;    // 16 B units (8 bf16)

    u64x2v vA = base[(r00 + c0 + xo0) >> 3];      // z0,x0 row
    u64x2v vB = base[(r01 + c0 + xo1) >> 3];      // z0,x1 row
    u64x2v vC = base[(r10 + c0 + xo0) >> 3];      // z1,x0 row
    u64x2v vD = base[(r11 + c0 + xo1) >> 3];      // z1,x1 row

    u64x2v vA2 = vA, vB2 = vB, vC2 = vC, vD2 = vD;
    if (c1 != c0) {                               // y-pair crosses the 8-tile (1/8 of lanes)
        vA2 = base[(r00 + c1 + xo0) >> 3];
        vB2 = base[(r01 + c1 + xo1) >> 3];
        vC2 = base[(r10 + c1 + xo0) >> 3];
        vD2 = base[(r11 + c1 + xo1) >> 3];
    }

    return
        extract_bf16(vA,  yo0) * w000 + extract_bf16(vA2, yo1) * w001 +
        extract_bf16(vB,  yo0) * w010 + extract_bf16(vB2, yo1) * w011 +
        extract_bf16(vC,  yo0) * w100 + extract_bf16(vC2, yo1) * w101 +
        extract_bf16(vD,  yo0) * w110 + extract_bf16(vD2, yo1) * w111;
}

// ---------------- kernel 1: albedo repack + out_n constant fill ----------------
// grid = 16384 (repack) + FB (out_n fill)
__global__ __launch_bounds__(256) void repack_fill_kernel(
    const float* __restrict__ albedo,
    unsigned short* __restrict__ tiled,
    float* __restrict__ out_n,
    int M, int FB)
{
    unsigned int b = blockIdx.x;

    if (b < 16384u) {
        // repack role: one block per (z, x-tile)
        int z = (int)(b >> 7);
        int xt = (int)(b & 127u);

        __shared__ float s[2048];             // 4 x-rows x 512 y
        const u32x4* src = (const u32x4*)(albedo + ((size_t)z * NR + (size_t)xt * 4) * NR);
        for (int k = threadIdx.x; k < 512; k += 256) {
            u32x4 v = __builtin_nontemporal_load(&src[k]);
            ((u32x4*)s)[k] = v;
        }
        __syncthreads();

        unsigned short* dst = tiled + (size_t)b * 2048;
        int t8 = threadIdx.x * 8;
        u16x8 outv;
#pragma unroll
        for (int j = 0; j < 8; j++) {
            int k = t8 + j;
            int yt = k >> 5;
            int r = k & 31;
            int xr = r >> 3;
            int yy = r & 7;
            outv[j] = f32_to_bf16_rne(s[xr * 512 + (yt << 3) + yy]);
        }
        *(u16x8*)(dst + t8) = outv;           // tiled IS re-read: keep cacheable
        return;
    }
    b -= 16384u;

    // out_n constant-pattern fill role (valid iff flag==0; else overwritten by normal_full)
    long long total = 3LL * M;
    if ((M & 3) == 0) {
        long long f4 = (long long)b * 256 + threadIdx.x;
        long long nf4 = total >> 2;
        if (f4 < nf4) {
            const unsigned int B = 0xBF800000u;   // -1.0f
            int rmod = (int)(f4 % 3);
            u32x4 v;
            if (rmod == 0)      v = (u32x4){B, 0u, 0u, B};
            else if (rmod == 1) v = (u32x4){0u, 0u, B, 0u};
            else                v = (u32x4){0u, B, 0u, 0u};
            __builtin_nontemporal_store(v, &((u32x4*)out_n)[f4]);
        }
    } else {
        long long stride = (long long)FB * 256;
        for (long long qq = (long long)b * 256 + threadIdx.x; qq < total; qq += stride)
            out_n[qq] = ((qq % 3) == 0) ? -1.0f : 0.0f;
    }
}

// ---------------- kernel 2: interp ∥ zcheck, interleaved 2:1 at block level ----------------
// grid = 3*ZB; b%3==2 -> zcheck block q=b/3 of ZB; else interp block ib=2q+(b%3) of IB=2*ZB.
// Co-schedules the latency-bound gather with the BW-bound normal stream on every CU.
__global__ __launch_bounds__(256) void interp_zcheck_kernel(
    const float* __restrict__ coords,
    const unsigned short* __restrict__ tiled,
    const u32x4* __restrict__ normal4,
    const unsigned int* __restrict__ normal_tail, int tail_cnt,
    unsigned int* __restrict__ flag,
    float* __restrict__ out_a,
    int M, long long n4, int ZB)
{
    unsigned int b = blockIdx.x;
    unsigned int q = b / 3u;
    unsigned int r = b - 3u * q;

    if (r == 2u) {
        if (q == 0 && threadIdx.x < (unsigned)tail_cnt) {
            if (normal_tail[threadIdx.x]) atomicOr(flag, 1u);
        }
        zcheck_range(normal4, 0, n4, (long long)q, (long long)ZB * 256, flag);
        return;
    }

    int ib = (int)(2u * q + r);
    int t = ib * 256 + (int)threadIdx.x;
    int i0 = t * 2;
    if (i0 >= M) return;

    // coords for 2 points: 6 consecutive floats, 8 B aligned (i0 even)
    const float2* cp = (const float2*)(coords + (size_t)i0 * 3);
    float2 q0 = cp[0], q1 = cp[1], q2 = cp[2];

    float a0 = interp_rows(tiled, q0.x, q0.y, q1.x);
    a0 = (a0 > 0.0f) ? a0 : expm1f(a0);

    if (i0 + 1 < M) {
        float a1 = interp_rows(tiled, q1.y, q2.x, q2.y);
        a1 = (a1 > 0.0f) ? a1 : expm1f(a1);
        f32x2 av; av.x = a0; av.y = a1;
        __builtin_nontemporal_store(av, (f32x2*)(out_a + i0));
    } else {
        out_a[i0] = a0;
    }
}

// ---------------- slow path: recompute out_n when `normal` has content ----------------
__global__ __launch_bounds__(256) void normal_full_kernel(
    const float* __restrict__ coords,
    const float* __restrict__ normal,
    const unsigned int* __restrict__ flag,
    float* __restrict__ out_n,
    int M)
{
    if (*flag == 0) return;

    int stride = gridDim.x * 256;
    for (int i = blockIdx.x * 256 + threadIdx.x; i < M; i += stride) {
        float cz = coords[3 * i + 0];
        float cx = coords[3 * i + 1];
        float cy = coords[3 * i + 2];

        float fz0 = floorf(cz), fx0 = floorf(cx), fy0 = floorf(cy);
        float fz = cz - fz0, fx = cx - fx0, fy = cy - fy0;

        int z0 = min(max((int)fz0, 0), ZR - 1);
        int x0 = min(max((int)fx0, 0), NR - 1);
        int y0 = min(max((int)fy0, 0), NR - 1);
        int z1 = min(z0 + 1, ZR - 1);
        int x1 = min(x0 + 1, NR - 1);
        int y1 = min(y0 + 1, NR - 1);

        float gz = 1.0f - fz, gx = 1.0f - fx, gy = 1.0f - fy;

        float w000 = gz * gx * gy, w001 = gz * gx * fy;
        float w010 = gz * fx * gy, w011 = gz * fx * fy;
        float w100 = fz * gx * gy, w101 = fz * gx * fy;
        float w110 = fz * fx * gy, w111 = fz * fx * fy;

        size_t b00 = ((size_t)z0 * NR + x0) * NR;
        size_t b01 = ((size_t)z0 * NR + x1) * NR;
        size_t b10 = ((size_t)z1 * NR + x0) * NR;
        size_t b11 = ((size_t)z1 * NR + x1) * NR;

        float n0 = 0.0f, n1 = 0.0f, n2 = 0.0f;
#define ACC(base, yy, w)                                           \
        {                                                          \
            const float* qp = normal + ((base) + (size_t)(yy)) * 3;\
            n0 += qp[0] * (w);                                     \
            n1 += qp[1] * (w);                                     \
            n2 += qp[2] * (w);                                     \
        }
        ACC(b00, y0, w000); ACC(b00, y1, w001);
        ACC(b01, y0, w010); ACC(b01, y1, w011);
        ACC(b10, y0, w100); ACC(b10, y1, w101);
        ACC(b11, y0, w110); ACC(b11, y1, w111);
#undef ACC

        n0 = tanhf(n0) - 1.0f;
        n1 = tanhf(n1);
        n2 = tanhf(n2);

        float nrm = sqrtf(n0 * n0 + n1 * n1 + n2 * n2);
        nrm = fmaxf(nrm, 1e-12f);
        float inv = 1.0f / nrm;

        out_n[3 * i + 0] = n0 * inv;
        out_n[3 * i + 1] = n1 * inv;
        out_n[3 * i + 2] = n2 * inv;
    }
}

// ---------------- fallback: fully general direct kernel (ws too small) ----------------
__global__ __launch_bounds__(256) void devox_direct(
    const float* __restrict__ coords,
    const float* __restrict__ albedo,
    const float* __restrict__ normal,
    float* __restrict__ out_a,
    float* __restrict__ out_n,
    int M)
{
    int i = blockIdx.x * 256 + threadIdx.x;
    if (i >= M) return;

    float cz = coords[3 * i + 0];
    float cx = coords[3 * i + 1];
    float cy = coords[3 * i + 2];

    float fz0 = floorf(cz), fx0 = floorf(cx), fy0 = floorf(cy);
    float fz = cz - fz0, fx = cx - fx0, fy = cy - fy0;

    int z0 = min(max((int)fz0, 0), ZR - 1);
    int x0 = min(max((int)fx0, 0), NR - 1);
    int y0 = min(max((int)fy0, 0), NR - 1);
    int z1 = min(z0 + 1, ZR - 1);
    int x1 = min(x0 + 1, NR - 1);
    int y1 = min(y0 + 1, NR - 1);

    float gz = 1.0f - fz, gx = 1.0f - fx, gy = 1.0f - fy;
    float w000 = gz * gx * gy, w001 = gz * gx * fy;
    float w010 = gz * fx * gy, w011 = gz * fx * fy;
    float w100 = fz * gx * gy, w101 = fz * gx * fy;
    float w110 = fz * fx * gy, w111 = fz * fx * fy;

    size_t b00 = ((size_t)z0 * NR + x0) * NR;
    size_t b01 = ((size_t)z0 * NR + x1) * NR;
    size_t b10 = ((size_t)z1 * NR + x0) * NR;
    size_t b11 = ((size_t)z1 * NR + x1) * NR;

    float a =
        albedo[b00 + y0] * w000 + albedo[b00 + y1] * w001 +
        albedo[b01 + y0] * w010 + albedo[b01 + y1] * w011 +
        albedo[b10 + y0] * w100 + albedo[b10 + y1] * w101 +
        albedo[b11 + y0] * w110 + albedo[b11 + y1] * w111;

    float n0 = 0.0f, n1 = 0.0f, n2 = 0.0f;
#define ACC(base, yy, w)                                           \
    {                                                              \
        const float* qp = normal + ((base) + (size_t)(yy)) * 3;    \
        n0 += qp[0] * (w);                                         \
        n1 += qp[1] * (w);                                         \
        n2 += qp[2] * (w);                                         \
    }
    ACC(b00, y0, w000); ACC(b00, y1, w001);
    ACC(b01, y0, w010); ACC(b01, y1, w011);
    ACC(b10, y0, w100); ACC(b10, y1, w101);
    ACC(b11, y0, w110); ACC(b11, y1, w111);
#undef ACC

    a = (a > 0.0f) ? a : expm1f(a);
    n0 = tanhf(n0) - 1.0f;
    n1 = tanhf(n1);
    n2 = tanhf(n2);
    float nrm = sqrtf(n0 * n0 + n1 * n1 + n2 * n2);
    nrm = fmaxf(nrm, 1e-12f);
    float inv = 1.0f / nrm;

    out_a[i] = a;
    out_n[3 * i + 0] = n0 * inv;
    out_n[3 * i + 1] = n1 * inv;
    out_n[3 * i + 2] = n2 * inv;
}

extern "C" void kernel_launch(void* const* d_in, const int* in_sizes, int n_in,
                              void* d_out, int out_size, void* d_ws, size_t ws_size,
                              hipStream_t stream) {
    const float* coords = (const float*)d_in[0];
    const float* albedo = (const float*)d_in[1];
    const float* normal = (const float*)d_in[2];

    int M = in_sizes[0] / 3;
    long long normal_elems = (long long)in_sizes[2];
    long long n4 = normal_elems / 4;
    int tail_cnt = (int)(normal_elems & 3);
    const unsigned int* normal_tail = (const unsigned int*)normal + n4 * 4;

    float* out = (float*)d_out;
    float* out_a = out;
    float* out_n = out + M;

    // ws: [flag u32][pad 256][tiled bf16 albedo: 33,554,432 u16 = 64 MiB]
    size_t tiled_off = 256;
    size_t tiled_bytes = (size_t)128 * 128 * 64 * 32 * 2;
    if (ws_size < tiled_off + tiled_bytes) {
        int nblk = (M + 255) / 256;
        devox_direct<<<nblk, 256, 0, stream>>>(coords, albedo, normal, out_a, out_n, M);
        return;
    }

    unsigned int* flag = (unsigned int*)d_ws;
    unsigned short* tiled = (unsigned short*)((char*)d_ws + tiled_off);

    (void)hipMemsetAsync(flag, 0, sizeof(unsigned int), stream);

    // kernel 1: repack (16384 blk) + out_n fill (FB blk)
    long long total_n = 3LL * M;
    int FB = ((M & 3) == 0) ? (int)((total_n / 4 + 255) / 256) : 2048;
    if (FB < 1) FB = 1;
    repack_fill_kernel<<<16384 + FB, 256, 0, stream>>>(albedo, tiled, out_n, M, FB);

    // kernel 2: interp (2 pt/thread, IB=2*ZB blocks) interleaved 2:1 with zcheck (ZB blocks)
    int IB = (M + 511) / 512;
    IB = (IB + 1) & ~1;                      // even, so the 2:1 triplet pattern is exact
    if (IB < 2) IB = 2;
    int ZB = IB / 2;
    interp_zcheck_kernel<<<3 * ZB, 256, 0, stream>>>(
        coords, tiled, (const u32x4*)normal, normal_tail, tail_cnt,
        flag, out_a, M, n4, ZB);

    // slow path (only does work when normal grid has nonzero content)
    normal_full_kernel<<<2048, 256, 0, stream>>>(coords, normal, flag, out_n, M);
}